// Round 8
// baseline (255.559 us; speedup 1.0000x reference)
//
#include <hip/hip_runtime.h>
#include <hip/hip_bf16.h>

#define NN 50000
#define NE 600000
#define CPAD 16  // one 4B counter per 64B line
// dims: in=128, hid=128, policy hidden=64, out=2

typedef __attribute__((ext_vector_type(8))) short short8;     // 8 bf16 (4 VGPRs)
typedef __attribute__((ext_vector_type(8))) _Float16 half8;   // 8 fp16
typedef __attribute__((ext_vector_type(4))) float floatx4;    // 4 f32 acc

__device__ __forceinline__ short bf16_bits(float v) {
    __hip_bfloat16 h = __float2bfloat16(v);
    return *reinterpret_cast<short*>(&h);
}

// stage 128x128 bf16 weight into LDS, XOR-swizzled 16B chunks (ci ^= row&7)
// so ds_read_b128 fragment reads spread evenly over all 8 bank-groups.
__device__ __forceinline__ void stage_w(const short* __restrict__ src, short* lds) {
    int t = threadIdx.x;
#pragma unroll
    for (int i = 0; i < 8; ++i) {
        int gci = t + i * 256;           // 2048 chunks of 8 shorts
        int row = gci >> 4, ci = gci & 15;
        short8 v = *(const short8*)(src + gci * 8);
        *(short8*)(lds + row * 128 + ((ci ^ (row & 7)) << 3)) = v;
    }
}

// ---------------- init: zero padded count + bsums + detect layout + convert weights ----------------
__global__ void k_init_cvt(const int* __restrict__ raw, int* __restrict__ count,
                           int* __restrict__ flag, int* __restrict__ bsums,
                           const float* __restrict__ wp1,
                           const float* __restrict__ w1, const float* __restrict__ w2,
                           __hip_bfloat16* __restrict__ wcatb, __hip_bfloat16* __restrict__ w1b,
                           __hip_bfloat16* __restrict__ w2b) {
    int i = blockIdx.x * blockDim.x + threadIdx.x;
    if (i < NN) {
        count[(size_t)i * CPAD] = 0;
    }
    if (i < 128) bsums[i] = 0;  // lookback scan: 0 = not ready
    if (i < 16384) {
        int r = i >> 7, c = i & 127;
        float v = (r < 64) ? wp1[r * 256 + c] : wp1[(r - 64) * 256 + 128 + c];
        wcatb[i] = __float2bfloat16(v);
    } else if (i < 32768) {
        w1b[i - 16384] = __float2bfloat16(w1[i - 16384]);
    } else if (i < 49152) {
        w2b[i - 32768] = __float2bfloat16(w2[i - 32768]);
    }
    if (blockIdx.x == 0) {
        if (threadIdx.x == 0) *flag = 0;
        __syncthreads();
        int any = 0;
        for (int j = threadIdx.x; j < 1024; j += 256) any |= raw[2 * j + 1];
        if (any) atomicOr(flag, 1);  // flag=1 -> int32 layout
    }
}

// ---------------- merged: batched count+rank (prefix blocks) + uv GEMM ----------------
#define GCNT 293  // ceil(NE / (256*8))
#define GG 782    // ceil(3125/4)
__global__ __launch_bounds__(256) void k_uv_cnt(
    const float* __restrict__ x, const __hip_bfloat16* __restrict__ Wb,
    const float* __restrict__ bp1, _Float16* __restrict__ uvh,
    __hip_bfloat16* __restrict__ xb, const int* __restrict__ raw,
    const int* __restrict__ flag, int* __restrict__ count, int* __restrict__ rank) {
    if (blockIdx.x < GCNT) {
        const bool f32 = (*flag) != 0;
        const long long* r64 = (const long long*)raw;
        int gid = blockIdx.x * 256 + threadIdx.x;
        int e0 = gid * 8;
        if (e0 + 8 <= NE) {
            int dd[8];
            if (f32) {
#pragma unroll
                for (int k = 0; k < 8; ++k) dd[k] = raw[NE + e0 + k];
            } else {
#pragma unroll
                for (int k = 0; k < 8; ++k) dd[k] = (int)r64[NE + e0 + k];
            }
            int rk[8];
#pragma unroll
            for (int k = 0; k < 8; ++k) rk[k] = atomicAdd(&count[(size_t)dd[k] * CPAD], 1);
#pragma unroll
            for (int k = 0; k < 8; ++k) rank[e0 + k] = rk[k];
        } else {
            for (int e = e0; e < NE; ++e) {
                int d = f32 ? raw[NE + e] : (int)r64[NE + e];
                rank[e] = atomicAdd(&count[(size_t)d * CPAD], 1);
            }
        }
        return;
    }
    __shared__ short wlds[16384];  // 32 KB
    stage_w((const short*)Wb, wlds);
    __syncthreads();

    const int lane = threadIdx.x & 63;
    const int wave = threadIdx.x >> 6;
    const int col = lane & 15;
    const int quad = lane >> 4;

    int tile = (blockIdx.x - GCNT) * 4 + wave;
    if (tile >= NN / 16) return;
    int base = tile * 16;

    short8 bfrag[4][8];
    const int rx = col & 7;
#pragma unroll
    for (int tt = 0; tt < 8; ++tt) {
        int row = tt * 16 + col;
#pragma unroll
        for (int kk = 0; kk < 4; ++kk)
            bfrag[kk][tt] = *(const short8*)(wlds + row * 128 + (((kk * 4 + quad) ^ rx) << 3));
    }

    floatx4 acc[8];
#pragma unroll
    for (int t = 0; t < 8; ++t) acc[t] = (floatx4){0.f, 0.f, 0.f, 0.f};
#pragma unroll
    for (int kk = 0; kk < 4; ++kk) {
        const float* xrow = x + (size_t)(base + col) * 128 + kk * 32 + quad * 8;
        float4 f0 = ((const float4*)xrow)[0];
        float4 f1 = ((const float4*)xrow)[1];
        short8 afrag;
        afrag[0] = bf16_bits(f0.x); afrag[1] = bf16_bits(f0.y);
        afrag[2] = bf16_bits(f0.z); afrag[3] = bf16_bits(f0.w);
        afrag[4] = bf16_bits(f1.x); afrag[5] = bf16_bits(f1.y);
        afrag[6] = bf16_bits(f1.z); afrag[7] = bf16_bits(f1.w);
        *(short8*)((short*)xb + (size_t)(base + col) * 128 + kk * 32 + quad * 8) = afrag;
#pragma unroll
        for (int tt = 0; tt < 8; ++tt)
            acc[tt] = __builtin_amdgcn_mfma_f32_16x16x32_bf16(afrag, bfrag[kk][tt], acc[tt], 0, 0, 0);
    }
#pragma unroll
    for (int tt = 0; tt < 8; ++tt) {
        int n = tt * 16 + col;
        float badd = (tt >= 4) ? bp1[n - 64] : 0.f;
#pragma unroll
        for (int r = 0; r < 4; ++r) {
            int row = base + quad * 4 + r;
            uvh[(size_t)row * 128 + n] = (_Float16)(acc[tt][r] + badd);
        }
    }
}

// ---------------- fused scan: decoupled lookback, 98 co-resident blocks -> rowptr ----------------
__global__ __launch_bounds__(512) void k_scan_rowptr(
    const int* __restrict__ count, int* __restrict__ bsums, int* __restrict__ rowptr) {
    __shared__ int s[512];
    __shared__ int red[512];
    int tid = threadIdx.x, bid = blockIdx.x;
    int i = bid * 512 + tid;
    s[tid] = (i < NN) ? count[(size_t)i * CPAD] : 0;
    __syncthreads();
    for (int off = 1; off < 512; off <<= 1) {
        int t = (tid >= off) ? s[tid - off] : 0;
        __syncthreads();
        s[tid] += t;
        __syncthreads();
    }
    if (tid == 511) atomicExch(&bsums[bid], s[511] + 1);  // publish (value+1, 0=not ready)
    int part = 0;
    for (int j = tid; j < bid; j += 512) {  // bid<98<512: at most one j per thread
        int v;
        do { v = atomicAdd(&bsums[j], 0); } while (v == 0);
        part += v - 1;
    }
    red[tid] = part;
    __syncthreads();
    for (int off = 256; off > 0; off >>= 1) {
        if (tid < off) red[tid] += red[tid + off];
        __syncthreads();
    }
    int prefix = red[0];
    if (i < NN) rowptr[i + 1] = s[tid] + prefix;
    if (bid == 0 && tid == 0) rowptr[0] = 0;
}

// ---------------- merged: edge-ordered policy MLP + direct CSR fill ----------------
#define GPOL 9375  // NE / 64, exact
__global__ __launch_bounds__(256) void k_pol_fill(
    const int* __restrict__ raw, const int* __restrict__ flag,
    const int* __restrict__ rank, const int* __restrict__ rowptr,
    const _Float16* __restrict__ uvh, const float* __restrict__ wp2,
    const float* __restrict__ bp2, int2* __restrict__ meta) {
    const bool f32 = (*flag) != 0;
    const long long* r64 = (const long long*)raw;
    int pb = blockIdx.x;
    int wave = threadIdx.x >> 6, lane = threadIdx.x & 63;
    int g = lane >> 3, c = lane & 7;
    int e1 = pb * 64 + wave * 16 + g;  // exact coverage, no tail
    int e2 = e1 + 8;
    int s1, d1, s2, d2;
    if (f32) {
        s1 = raw[e1]; d1 = raw[NE + e1];
        s2 = raw[e2]; d2 = raw[NE + e2];
    } else {
        s1 = (int)r64[e1]; d1 = (int)r64[NE + e1];
        s2 = (int)r64[e2]; d2 = (int)r64[NE + e2];
    }
    half8 u1 = *(const half8*)(uvh + (size_t)s1 * 128 + c * 8);
    half8 v1 = *(const half8*)(uvh + (size_t)d1 * 128 + 64 + c * 8);
    half8 u2 = *(const half8*)(uvh + (size_t)s2 * 128 + c * 8);
    half8 v2 = *(const half8*)(uvh + (size_t)d2 * 128 + 64 + c * 8);
    float w2v[8];
    const float4* w2p = (const float4*)(wp2 + c * 8);
    float4 wa = w2p[0], wb = w2p[1];
    w2v[0] = wa.x; w2v[1] = wa.y; w2v[2] = wa.z; w2v[3] = wa.w;
    w2v[4] = wb.x; w2v[5] = wb.y; w2v[6] = wb.z; w2v[7] = wb.w;
    float b2 = bp2[0];
    float p1 = 0.f, p2 = 0.f;
#pragma unroll
    for (int j = 0; j < 8; ++j) {
        float h1 = (float)u1[j] + (float)v1[j];
        float h2 = (float)u2[j] + (float)v2[j];
        h1 = h1 > 0.f ? h1 : 0.f;
        h2 = h2 > 0.f ? h2 : 0.f;
        p1 += h1 * w2v[j];
        p2 += h2 * w2v[j];
    }
    p1 += __shfl_xor(p1, 1, 64); p2 += __shfl_xor(p2, 1, 64);
    p1 += __shfl_xor(p1, 2, 64); p2 += __shfl_xor(p2, 2, 64);
    p1 += __shfl_xor(p1, 4, 64); p2 += __shfl_xor(p2, 4, 64);
    if (c == 0) {
        float ew1 = 1.f / (1.f + __expf(-(p1 + b2)));
        float ew2 = 1.f / (1.f + __expf(-(p2 + b2)));
        int rk1 = rank[e1], rk2 = rank[e2];
        int rb1 = rowptr[d1], rb2 = rowptr[d2];
        meta[rb1 + rk1] = make_int2(s1, __float_as_int(ew1));
        meta[rb2 + rk2] = make_int2(s2, __float_as_int(ew2));
    }
}

// ---------------- GCN feature transform: xl' = dinv * (A_in @ W^T) (fp16); W from LDS ----------------
// CDEG=true also computes deg = 1 + segment_sum(ew) from meta (layer 1).
template <bool CDEG>
__global__ __launch_bounds__(256) void k_gemm(
    const __hip_bfloat16* __restrict__ A, const __hip_bfloat16* __restrict__ Wb,
    const int* __restrict__ rowptr, const int2* __restrict__ meta,
    float* __restrict__ deg, _Float16* __restrict__ xlh) {
    __shared__ short wlds[16384];  // 32 KB
    stage_w((const short*)Wb, wlds);
    __syncthreads();

    const int lane = threadIdx.x & 63;
    const int wave = threadIdx.x >> 6;
    const int col = lane & 15;
    const int quad = lane >> 4;

    int tile = blockIdx.x * 4 + wave;
    if (tile >= NN / 16) return;  // 3125 tiles
    int base = tile * 16;

    short8 bfrag[4][8];
    const int rx = col & 7;
#pragma unroll
    for (int tt = 0; tt < 8; ++tt) {
        int row = tt * 16 + col;
#pragma unroll
        for (int kk = 0; kk < 4; ++kk)
            bfrag[kk][tt] = *(const short8*)(wlds + row * 128 + (((kk * 4 + quad) ^ rx) << 3));
    }
    const short* xs = (const short*)A;

    floatx4 acc[8];
#pragma unroll
    for (int t = 0; t < 8; ++t) acc[t] = (floatx4){0.f, 0.f, 0.f, 0.f};
#pragma unroll
    for (int kk = 0; kk < 4; ++kk) {
        short8 afrag = *(const short8*)(xs + (size_t)(base + col) * 128 + kk * 32 + quad * 8);
#pragma unroll
        for (int tt = 0; tt < 8; ++tt)
            acc[tt] = __builtin_amdgcn_mfma_f32_16x16x32_bf16(afrag, bfrag[kk][tt], acc[tt], 0, 0, 0);
    }
    float di[4];
    if (CDEG) {
        int rn = base + col;
        int beg = rowptr[rn], end = rowptr[rn + 1];
        float sdeg = 0.f;
        for (int p = beg + quad; p < end; p += 4) sdeg += __int_as_float(meta[p].y);
        sdeg += __shfl_xor(sdeg, 16, 64);
        sdeg += __shfl_xor(sdeg, 32, 64);
        float dv = 1.f + sdeg;
        if (quad == 0) deg[rn] = dv;  // lanes 0..15: coalesced
#pragma unroll
        for (int r = 0; r < 4; ++r) di[r] = rsqrtf(__shfl(dv, quad * 4 + r, 64));
    } else {
#pragma unroll
        for (int r = 0; r < 4; ++r) di[r] = rsqrtf(deg[base + quad * 4 + r]);
    }
#pragma unroll
    for (int tt = 0; tt < 8; ++tt) {
        int n = tt * 16 + col;
#pragma unroll
        for (int r = 0; r < 4; ++r) {
            int row = base + quad * 4 + r;
            xlh[(size_t)row * 128 + n] = (_Float16)(di[r] * acc[tt][r]);
        }
    }
}

// ---------------- scatter core v2: wave per node, 8 edge-groups of 8 lanes ----------------
// Each lane covers 16 features (2x half8), unroll 2 -> 4 independent 16B loads in flight.
// deg~12 node: one round of <=2 parallel edges per group (vs ~2.5 serial rounds before).
__device__ __forceinline__ void scatter_core8(
    const int* __restrict__ rowptr, const int2* __restrict__ meta,
    const _Float16* __restrict__ xlh, int wid, int g, int c, float acc[16]) {
    int beg = rowptr[wid], end = rowptr[wid + 1];
    int p = beg + g;
    for (; p + 8 < end; p += 16) {
        int2 m1 = meta[p], m2 = meta[p + 8];
        const _Float16* q1 = xlh + (size_t)m1.x * 128 + c * 16;
        const _Float16* q2 = xlh + (size_t)m2.x * 128 + c * 16;
        half8 a1 = *(const half8*)q1;
        half8 b1 = *(const half8*)(q1 + 8);
        half8 a2 = *(const half8*)q2;
        half8 b2 = *(const half8*)(q2 + 8);
        float c1 = __int_as_float(m1.y), c2 = __int_as_float(m2.y);
#pragma unroll
        for (int j = 0; j < 8; ++j) {
            acc[j]     += c1 * (float)a1[j] + c2 * (float)a2[j];
            acc[j + 8] += c1 * (float)b1[j] + c2 * (float)b2[j];
        }
    }
    if (p < end) {
        int2 m1 = meta[p];
        const _Float16* q1 = xlh + (size_t)m1.x * 128 + c * 16;
        half8 a1 = *(const half8*)q1;
        half8 b1 = *(const half8*)(q1 + 8);
        float c1 = __int_as_float(m1.y);
#pragma unroll
        for (int j = 0; j < 8; ++j) {
            acc[j]     += c1 * (float)a1[j];
            acc[j + 8] += c1 * (float)b1[j];
        }
    }
#pragma unroll
    for (int j = 0; j < 16; ++j) {
        acc[j] += __shfl_xor(acc[j], 8, 64);
        acc[j] += __shfl_xor(acc[j], 16, 64);
        acc[j] += __shfl_xor(acc[j], 32, 64);
    }
}

// mid-layer scatter: epilogue reconstructs bias + self-loop, emits relu as bf16
__global__ __launch_bounds__(256) void k_scatter_mid(
    const int* __restrict__ rowptr, const int2* __restrict__ meta,
    const float* __restrict__ deg, const _Float16* __restrict__ xlh,
    const float* __restrict__ bias, __hip_bfloat16* __restrict__ xb2) {
    int wid = (blockIdx.x * blockDim.x + threadIdx.x) >> 6;
    int lane = threadIdx.x & 63;
    if (wid >= NN) return;
    int g = lane >> 3, c = lane & 7;
    float acc[16];
#pragma unroll
    for (int j = 0; j < 16; ++j) acc[j] = 0.f;
    scatter_core8(rowptr, meta, xlh, wid, g, c, acc);
    if (g == 0) {
        float dn = rsqrtf(deg[wid]);
        const _Float16* sp = xlh + (size_t)wid * 128 + c * 16;  // pre-scaled self row
        half8 s0 = *(const half8*)sp;
        half8 s1 = *(const half8*)(sp + 8);
        const float4* bp = (const float4*)(bias + c * 16);
        float4 ba = bp[0], bb = bp[1], bc = bp[2], bd = bp[3];
        float bv[16] = {ba.x, ba.y, ba.z, ba.w, bb.x, bb.y, bb.z, bb.w,
                        bc.x, bc.y, bc.z, bc.w, bd.x, bd.y, bd.z, bd.w};
        short8 o0, o1;
#pragma unroll
        for (int j = 0; j < 8; ++j) {
            float t = bv[j] + dn * ((float)s0[j] + acc[j]);
            t = t > 0.f ? t : 0.f;
            o0[j] = bf16_bits(t);
            float u = bv[j + 8] + dn * ((float)s1[j] + acc[j + 8]);
            u = u > 0.f ? u : 0.f;
            o1[j] = bf16_bits(u);
        }
        short* op = (short*)xb2 + (size_t)wid * 128 + c * 16;
        *(short8*)op = o0;
        *(short8*)(op + 8) = o1;
    }
}

// final scatter fused with output head: sigmoid(relu(h2) @ Wlin^T + blin)
__global__ __launch_bounds__(256) void k_scatter_out(
    const int* __restrict__ rowptr, const int2* __restrict__ meta,
    const float* __restrict__ deg, const _Float16* __restrict__ xlh,
    const float* __restrict__ bias, const float* __restrict__ wlin,
    const float* __restrict__ blin, float* __restrict__ out) {
    int wid = (blockIdx.x * blockDim.x + threadIdx.x) >> 6;
    int lane = threadIdx.x & 63;
    if (wid >= NN) return;
    int g = lane >> 3, c = lane & 7;
    float acc[16];
#pragma unroll
    for (int j = 0; j < 16; ++j) acc[j] = 0.f;
    scatter_core8(rowptr, meta, xlh, wid, g, c, acc);
    if (g == 0) {
        float dn = rsqrtf(deg[wid]);
        const _Float16* sp = xlh + (size_t)wid * 128 + c * 16;
        half8 s0 = *(const half8*)sp;
        half8 s1 = *(const half8*)(sp + 8);
        const float4* bp = (const float4*)(bias + c * 16);
        float4 ba = bp[0], bb = bp[1], bc = bp[2], bd = bp[3];
        float bv[16] = {ba.x, ba.y, ba.z, ba.w, bb.x, bb.y, bb.z, bb.w,
                        bc.x, bc.y, bc.z, bc.w, bd.x, bd.y, bd.z, bd.w};
        float p0 = 0.f, p1 = 0.f;
#pragma unroll
        for (int j = 0; j < 8; ++j) {
            float t = bv[j] + dn * ((float)s0[j] + acc[j]);
            t = t > 0.f ? t : 0.f;
            p0 += t * wlin[c * 16 + j];
            p1 += t * wlin[128 + c * 16 + j];
            float u = bv[j + 8] + dn * ((float)s1[j] + acc[j + 8]);
            u = u > 0.f ? u : 0.f;
            p0 += u * wlin[c * 16 + 8 + j];
            p1 += u * wlin[128 + c * 16 + 8 + j];
        }
        p0 += __shfl_xor(p0, 1, 64); p1 += __shfl_xor(p1, 1, 64);
        p0 += __shfl_xor(p0, 2, 64); p1 += __shfl_xor(p1, 2, 64);
        p0 += __shfl_xor(p0, 4, 64); p1 += __shfl_xor(p1, 4, 64);
        if (c == 0) {
            out[wid * 2 + 0] = 1.f / (1.f + __expf(-(p0 + blin[0])));
            out[wid * 2 + 1] = 1.f / (1.f + __expf(-(p1 + blin[1])));
        }
    }
}

// ---------------- host launcher ----------------

extern "C" void kernel_launch(void* const* d_in, const int* in_sizes, int n_in,
                              void* d_out, int out_size, void* d_ws, size_t ws_size,
                              hipStream_t stream) {
    const float* x = (const float*)d_in[0];
    const int* eidx_raw = (const int*)d_in[1];
    const float* W_p1 = (const float*)d_in[2];
    const float* b_p1 = (const float*)d_in[3];
    const float* W_p2 = (const float*)d_in[4];
    const float* b_p2 = (const float*)d_in[5];
    const float* W1 = (const float*)d_in[6];
    const float* b1 = (const float*)d_in[7];
    const float* W2 = (const float*)d_in[8];
    const float* b2 = (const float*)d_in[9];
    const float* W_lin = (const float*)d_in[10];
    const float* b_lin = (const float*)d_in[11];
    float* out = (float*)d_out;

    char* ws = (char*)d_ws;
    size_t off = 0;
    auto alloc = [&](size_t bytes) -> void* {
        off = (off + 255) & ~(size_t)255;
        void* p = ws + off;
        off += bytes;
        return p;
    };
    float* deg = (float*)alloc(NN * 4);
    int* rowptr = (int*)alloc((NN + 1) * 4);
    int* count = (int*)alloc((size_t)NN * CPAD * 4);  // line-padded histogram
    int* flag = (int*)alloc(4);
    int* bsums = (int*)alloc(128 * 4);
    int* rank = (int*)alloc((size_t)NE * 4);
    int2* meta = (int2*)alloc((size_t)NE * 8);
    __hip_bfloat16* xb = (__hip_bfloat16*)alloc((size_t)NN * 128 * 2);  // reused as xb2
    _Float16* xlh = (_Float16*)alloc((size_t)NN * 128 * 2);
    _Float16* uvh = (_Float16*)alloc((size_t)NN * 128 * 2);
    __hip_bfloat16* wcatb = (__hip_bfloat16*)alloc(128 * 128 * 2);
    __hip_bfloat16* w1b = (__hip_bfloat16*)alloc(128 * 128 * 2);
    __hip_bfloat16* w2b = (__hip_bfloat16*)alloc(128 * 128 * 2);

    const int TB = 256;
    int gN = (NN + TB - 1) / TB;        // 196
    int gS = (NN + 3) / 4;              // 12500

    // 1: weight cvt + count/bsums zero + layout flag
    k_init_cvt<<<gN, TB, 0, stream>>>(eidx_raw, count, flag, bsums, W_p1, W1, W2, wcatb, w1b, w2b);
    // 2: count+rank (prefix blocks, batched atomics) overlapped with uv GEMM
    k_uv_cnt<<<GCNT + GG, TB, 0, stream>>>(x, wcatb, b_p1, uvh, xb, eidx_raw, flag, count, rank);
    // 3: fused lookback scan -> rowptr
    k_scan_rowptr<<<98, 512, 0, stream>>>(count, bsums, rowptr);
    // 4: edge-ordered policy MLP + direct CSR fill
    k_pol_fill<<<GPOL, TB, 0, stream>>>(eidx_raw, flag, rank, rowptr, uvh, W_p2, b_p2, meta);
    // 5: layer-1 transform + deg (dinv folded into xlh)
    k_gemm<true><<<GG, TB, 0, stream>>>(xb, w1b, rowptr, meta, deg, xlh);
    // 6: layer-1 aggregate
    k_scatter_mid<<<gS, TB, 0, stream>>>(rowptr, meta, deg, xlh, b1, xb);
    // 7: layer-2 transform
    k_gemm<false><<<GG, TB, 0, stream>>>(xb, w2b, rowptr, meta, deg, xlh);
    // 8: layer-2 aggregate + output head
    k_scatter_out<<<gS, TB, 0, stream>>>(rowptr, meta, deg, xlh, b2, W_lin, b_lin, out);
}

// Round 9
// 235.518 us; speedup vs baseline: 1.0851x; 1.0851x over previous
//
#include <hip/hip_runtime.h>
#include <hip/hip_bf16.h>

#define NN 50000
#define NE 600000
#define CPAD 16  // one 4B counter per 64B line
// dims: in=128, hid=128, policy hidden=64, out=2

typedef __attribute__((ext_vector_type(8))) short short8;     // 8 bf16 (4 VGPRs)
typedef __attribute__((ext_vector_type(8))) _Float16 half8;   // 8 fp16
typedef __attribute__((ext_vector_type(4))) float floatx4;    // 4 f32 acc

__device__ __forceinline__ short bf16_bits(float v) {
    __hip_bfloat16 h = __float2bfloat16(v);
    return *reinterpret_cast<short*>(&h);
}

// stage 128x128 bf16 weight into LDS, XOR-swizzled 16B chunks (ci ^= row&7)
__device__ __forceinline__ void stage_w(const short* __restrict__ src, short* lds) {
    int t = threadIdx.x;
#pragma unroll
    for (int i = 0; i < 8; ++i) {
        int gci = t + i * 256;           // 2048 chunks of 8 shorts
        int row = gci >> 4, ci = gci & 15;
        short8 v = *(const short8*)(src + gci * 8);
        *(short8*)(lds + row * 128 + ((ci ^ (row & 7)) << 3)) = v;
    }
}

// ---------------- init: zero padded count + bsums + detect layout + convert weights ----------------
__global__ void k_init_cvt(const int* __restrict__ raw, int* __restrict__ count,
                           int* __restrict__ flag, int* __restrict__ bsums,
                           const float* __restrict__ wp1,
                           const float* __restrict__ w1, const float* __restrict__ w2,
                           __hip_bfloat16* __restrict__ wcatb, __hip_bfloat16* __restrict__ w1b,
                           __hip_bfloat16* __restrict__ w2b) {
    int i = blockIdx.x * blockDim.x + threadIdx.x;
    if (i < NN) {
        count[(size_t)i * CPAD] = 0;
    }
    if (i < 128) bsums[i] = 0;  // lookback scan: 0 = not ready
    if (i < 16384) {
        int r = i >> 7, c = i & 127;
        float v = (r < 64) ? wp1[r * 256 + c] : wp1[(r - 64) * 256 + 128 + c];
        wcatb[i] = __float2bfloat16(v);
    } else if (i < 32768) {
        w1b[i - 16384] = __float2bfloat16(w1[i - 16384]);
    } else if (i < 49152) {
        w2b[i - 32768] = __float2bfloat16(w2[i - 32768]);
    }
    if (blockIdx.x == 0) {
        if (threadIdx.x == 0) *flag = 0;
        __syncthreads();
        int any = 0;
        for (int j = threadIdx.x; j < 1024; j += 256) any |= raw[2 * j + 1];
        if (any) atomicOr(flag, 1);  // flag=1 -> int32 layout
    }
}

// ---------------- merged: batched count+rank (prefix blocks) + uv GEMM ----------------
#define GCNT 293  // ceil(NE / (256*8))
#define GG 782    // ceil(3125/4)
__global__ __launch_bounds__(256) void k_uv_cnt(
    const float* __restrict__ x, const __hip_bfloat16* __restrict__ Wb,
    const float* __restrict__ bp1, _Float16* __restrict__ uvh,
    __hip_bfloat16* __restrict__ xb, const int* __restrict__ raw,
    const int* __restrict__ flag, int* __restrict__ count, int* __restrict__ rank) {
    if (blockIdx.x < GCNT) {
        const bool f32 = (*flag) != 0;
        const long long* r64 = (const long long*)raw;
        int gid = blockIdx.x * 256 + threadIdx.x;
        int e0 = gid * 8;
        if (e0 + 8 <= NE) {
            int dd[8];
            if (f32) {
#pragma unroll
                for (int k = 0; k < 8; ++k) dd[k] = raw[NE + e0 + k];
            } else {
#pragma unroll
                for (int k = 0; k < 8; ++k) dd[k] = (int)r64[NE + e0 + k];
            }
            int rk[8];
#pragma unroll
            for (int k = 0; k < 8; ++k) rk[k] = atomicAdd(&count[(size_t)dd[k] * CPAD], 1);
#pragma unroll
            for (int k = 0; k < 8; ++k) rank[e0 + k] = rk[k];
        } else {
            for (int e = e0; e < NE; ++e) {
                int d = f32 ? raw[NE + e] : (int)r64[NE + e];
                rank[e] = atomicAdd(&count[(size_t)d * CPAD], 1);
            }
        }
        return;
    }
    __shared__ short wlds[16384];  // 32 KB
    stage_w((const short*)Wb, wlds);
    __syncthreads();

    const int lane = threadIdx.x & 63;
    const int wave = threadIdx.x >> 6;
    const int col = lane & 15;
    const int quad = lane >> 4;

    int tile = (blockIdx.x - GCNT) * 4 + wave;
    if (tile >= NN / 16) return;
    int base = tile * 16;

    short8 bfrag[4][8];
    const int rx = col & 7;
#pragma unroll
    for (int tt = 0; tt < 8; ++tt) {
        int row = tt * 16 + col;
#pragma unroll
        for (int kk = 0; kk < 4; ++kk)
            bfrag[kk][tt] = *(const short8*)(wlds + row * 128 + (((kk * 4 + quad) ^ rx) << 3));
    }

    floatx4 acc[8];
#pragma unroll
    for (int t = 0; t < 8; ++t) acc[t] = (floatx4){0.f, 0.f, 0.f, 0.f};
#pragma unroll
    for (int kk = 0; kk < 4; ++kk) {
        const float* xrow = x + (size_t)(base + col) * 128 + kk * 32 + quad * 8;
        float4 f0 = ((const float4*)xrow)[0];
        float4 f1 = ((const float4*)xrow)[1];
        short8 afrag;
        afrag[0] = bf16_bits(f0.x); afrag[1] = bf16_bits(f0.y);
        afrag[2] = bf16_bits(f0.z); afrag[3] = bf16_bits(f0.w);
        afrag[4] = bf16_bits(f1.x); afrag[5] = bf16_bits(f1.y);
        afrag[6] = bf16_bits(f1.z); afrag[7] = bf16_bits(f1.w);
        *(short8*)((short*)xb + (size_t)(base + col) * 128 + kk * 32 + quad * 8) = afrag;
#pragma unroll
        for (int tt = 0; tt < 8; ++tt)
            acc[tt] = __builtin_amdgcn_mfma_f32_16x16x32_bf16(afrag, bfrag[kk][tt], acc[tt], 0, 0, 0);
    }
#pragma unroll
    for (int tt = 0; tt < 8; ++tt) {
        int n = tt * 16 + col;
        float badd = (tt >= 4) ? bp1[n - 64] : 0.f;
#pragma unroll
        for (int r = 0; r < 4; ++r) {
            int row = base + quad * 4 + r;
            uvh[(size_t)row * 128 + n] = (_Float16)(acc[tt][r] + badd);
        }
    }
}

// ---------------- fused scan: decoupled lookback, 98 co-resident blocks -> rowptr ----------------
__global__ __launch_bounds__(512) void k_scan_rowptr(
    const int* __restrict__ count, int* __restrict__ bsums, int* __restrict__ rowptr) {
    __shared__ int s[512];
    __shared__ int red[512];
    int tid = threadIdx.x, bid = blockIdx.x;
    int i = bid * 512 + tid;
    s[tid] = (i < NN) ? count[(size_t)i * CPAD] : 0;
    __syncthreads();
    for (int off = 1; off < 512; off <<= 1) {
        int t = (tid >= off) ? s[tid - off] : 0;
        __syncthreads();
        s[tid] += t;
        __syncthreads();
    }
    if (tid == 511) atomicExch(&bsums[bid], s[511] + 1);  // publish (value+1, 0=not ready)
    int part = 0;
    for (int j = tid; j < bid; j += 512) {  // bid<98<512: at most one j per thread
        int v;
        do { v = atomicAdd(&bsums[j], 0); } while (v == 0);
        part += v - 1;
    }
    red[tid] = part;
    __syncthreads();
    for (int off = 256; off > 0; off >>= 1) {
        if (tid < off) red[tid] += red[tid + off];
        __syncthreads();
    }
    int prefix = red[0];
    if (i < NN) rowptr[i + 1] = s[tid] + prefix;
    if (bid == 0 && tid == 0) rowptr[0] = 0;
}

// ---------------- merged: edge-ordered policy MLP + direct CSR fill ----------------
#define GPOL 9375  // NE / 64, exact
__global__ __launch_bounds__(256) void k_pol_fill(
    const int* __restrict__ raw, const int* __restrict__ flag,
    const int* __restrict__ rank, const int* __restrict__ rowptr,
    const _Float16* __restrict__ uvh, const float* __restrict__ wp2,
    const float* __restrict__ bp2, int2* __restrict__ meta) {
    const bool f32 = (*flag) != 0;
    const long long* r64 = (const long long*)raw;
    int pb = blockIdx.x;
    int wave = threadIdx.x >> 6, lane = threadIdx.x & 63;
    int g = lane >> 3, c = lane & 7;
    int e1 = pb * 64 + wave * 16 + g;  // exact coverage, no tail
    int e2 = e1 + 8;
    int s1, d1, s2, d2;
    if (f32) {
        s1 = raw[e1]; d1 = raw[NE + e1];
        s2 = raw[e2]; d2 = raw[NE + e2];
    } else {
        s1 = (int)r64[e1]; d1 = (int)r64[NE + e1];
        s2 = (int)r64[e2]; d2 = (int)r64[NE + e2];
    }
    half8 u1 = *(const half8*)(uvh + (size_t)s1 * 128 + c * 8);
    half8 v1 = *(const half8*)(uvh + (size_t)d1 * 128 + 64 + c * 8);
    half8 u2 = *(const half8*)(uvh + (size_t)s2 * 128 + c * 8);
    half8 v2 = *(const half8*)(uvh + (size_t)d2 * 128 + 64 + c * 8);
    float w2v[8];
    const float4* w2p = (const float4*)(wp2 + c * 8);
    float4 wa = w2p[0], wb = w2p[1];
    w2v[0] = wa.x; w2v[1] = wa.y; w2v[2] = wa.z; w2v[3] = wa.w;
    w2v[4] = wb.x; w2v[5] = wb.y; w2v[6] = wb.z; w2v[7] = wb.w;
    float b2 = bp2[0];
    float p1 = 0.f, p2 = 0.f;
#pragma unroll
    for (int j = 0; j < 8; ++j) {
        float h1 = (float)u1[j] + (float)v1[j];
        float h2 = (float)u2[j] + (float)v2[j];
        h1 = h1 > 0.f ? h1 : 0.f;
        h2 = h2 > 0.f ? h2 : 0.f;
        p1 += h1 * w2v[j];
        p2 += h2 * w2v[j];
    }
    p1 += __shfl_xor(p1, 1, 64); p2 += __shfl_xor(p2, 1, 64);
    p1 += __shfl_xor(p1, 2, 64); p2 += __shfl_xor(p2, 2, 64);
    p1 += __shfl_xor(p1, 4, 64); p2 += __shfl_xor(p2, 4, 64);
    if (c == 0) {
        float ew1 = 1.f / (1.f + __expf(-(p1 + b2)));
        float ew2 = 1.f / (1.f + __expf(-(p2 + b2)));
        int rk1 = rank[e1], rk2 = rank[e2];
        int rb1 = rowptr[d1], rb2 = rowptr[d2];
        meta[rb1 + rk1] = make_int2(s1, __float_as_int(ew1));
        meta[rb2 + rk2] = make_int2(s2, __float_as_int(ew2));
    }
}

// ---------------- GCN feature transform: xl' = dinv * (A_in @ W^T) (fp16); W from LDS ----------------
// CDEG=true also computes deg = 1 + segment_sum(ew) from meta (layer 1).
template <bool CDEG>
__global__ __launch_bounds__(256) void k_gemm(
    const __hip_bfloat16* __restrict__ A, const __hip_bfloat16* __restrict__ Wb,
    const int* __restrict__ rowptr, const int2* __restrict__ meta,
    float* __restrict__ deg, _Float16* __restrict__ xlh) {
    __shared__ short wlds[16384];  // 32 KB
    stage_w((const short*)Wb, wlds);
    __syncthreads();

    const int lane = threadIdx.x & 63;
    const int wave = threadIdx.x >> 6;
    const int col = lane & 15;
    const int quad = lane >> 4;

    int tile = blockIdx.x * 4 + wave;
    if (tile >= NN / 16) return;  // 3125 tiles
    int base = tile * 16;

    short8 bfrag[4][8];
    const int rx = col & 7;
#pragma unroll
    for (int tt = 0; tt < 8; ++tt) {
        int row = tt * 16 + col;
#pragma unroll
        for (int kk = 0; kk < 4; ++kk)
            bfrag[kk][tt] = *(const short8*)(wlds + row * 128 + (((kk * 4 + quad) ^ rx) << 3));
    }
    const short* xs = (const short*)A;

    floatx4 acc[8];
#pragma unroll
    for (int t = 0; t < 8; ++t) acc[t] = (floatx4){0.f, 0.f, 0.f, 0.f};
#pragma unroll
    for (int kk = 0; kk < 4; ++kk) {
        short8 afrag = *(const short8*)(xs + (size_t)(base + col) * 128 + kk * 32 + quad * 8);
#pragma unroll
        for (int tt = 0; tt < 8; ++tt)
            acc[tt] = __builtin_amdgcn_mfma_f32_16x16x32_bf16(afrag, bfrag[kk][tt], acc[tt], 0, 0, 0);
    }
    float di[4];
    if (CDEG) {
        int rn = base + col;
        int beg = rowptr[rn], end = rowptr[rn + 1];
        float sdeg = 0.f;
        for (int p = beg + quad; p < end; p += 4) sdeg += __int_as_float(meta[p].y);
        sdeg += __shfl_xor(sdeg, 16, 64);
        sdeg += __shfl_xor(sdeg, 32, 64);
        float dv = 1.f + sdeg;
        if (quad == 0) deg[rn] = dv;  // lanes 0..15: coalesced
#pragma unroll
        for (int r = 0; r < 4; ++r) di[r] = rsqrtf(__shfl(dv, quad * 4 + r, 64));
    } else {
#pragma unroll
        for (int r = 0; r < 4; ++r) di[r] = rsqrtf(deg[base + quad * 4 + r]);
    }
#pragma unroll
    for (int tt = 0; tt < 8; ++tt) {
        int n = tt * 16 + col;
#pragma unroll
        for (int r = 0; r < 4; ++r) {
            int row = base + quad * 4 + r;
            xlh[(size_t)row * 128 + n] = (_Float16)(di[r] * acc[tt][r]);
        }
    }
}

// ---------------- scatter core v3: wave per node, 4 groups of 16 lanes, masked 4-deep ----------------
// One round covers 4 edges/group with 4 independent coalesced 16B gathers in flight.
// OOB slots clamp to edge-1's row (L1 hit) with coef 0 -> numerically exact.
// deg<=16: exactly ONE {meta -> gather -> fma} round (vs 2-3 serial rounds before).
__device__ __forceinline__ void scatter_core(
    const int* __restrict__ rowptr, const int2* __restrict__ meta,
    const _Float16* __restrict__ xlh, int wid, int g, int c, float acc[8]) {
    int beg = rowptr[wid], end = rowptr[wid + 1];
    for (int p = beg + g; p < end; p += 16) {
        int2 m1 = meta[p];
        int2 m2 = (p + 4  < end) ? meta[p + 4]  : make_int2(m1.x, 0);
        int2 m3 = (p + 8  < end) ? meta[p + 8]  : make_int2(m1.x, 0);
        int2 m4 = (p + 12 < end) ? meta[p + 12] : make_int2(m1.x, 0);
        half8 r1 = *(const half8*)(xlh + (size_t)m1.x * 128 + c * 8);
        half8 r2 = *(const half8*)(xlh + (size_t)m2.x * 128 + c * 8);
        half8 r3 = *(const half8*)(xlh + (size_t)m3.x * 128 + c * 8);
        half8 r4 = *(const half8*)(xlh + (size_t)m4.x * 128 + c * 8);
        float c1 = __int_as_float(m1.y), c2 = __int_as_float(m2.y);
        float c3 = __int_as_float(m3.y), c4 = __int_as_float(m4.y);
#pragma unroll
        for (int j = 0; j < 8; ++j)
            acc[j] += c1 * (float)r1[j] + c2 * (float)r2[j] + c3 * (float)r3[j] + c4 * (float)r4[j];
    }
#pragma unroll
    for (int j = 0; j < 8; ++j) {
        acc[j] += __shfl_xor(acc[j], 16, 64);
        acc[j] += __shfl_xor(acc[j], 32, 64);
    }
}

// mid-layer scatter: epilogue reconstructs bias + self-loop, emits relu as bf16
__global__ __launch_bounds__(256) void k_scatter_mid(
    const int* __restrict__ rowptr, const int2* __restrict__ meta,
    const float* __restrict__ deg, const _Float16* __restrict__ xlh,
    const float* __restrict__ bias, __hip_bfloat16* __restrict__ xb2) {
    int wid = (blockIdx.x * blockDim.x + threadIdx.x) >> 6;
    int lane = threadIdx.x & 63;
    if (wid >= NN) return;
    int g = lane >> 4, c = lane & 15;
    float acc[8] = {0.f, 0.f, 0.f, 0.f, 0.f, 0.f, 0.f, 0.f};
    scatter_core(rowptr, meta, xlh, wid, g, c, acc);
    if (g == 0) {
        float dn = rsqrtf(deg[wid]);
        half8 sv = *(const half8*)(xlh + (size_t)wid * 128 + c * 8);  // pre-scaled self row
        const float4* bp = (const float4*)(bias + c * 8);
        float4 ba = bp[0], bb = bp[1];
        float bv[8] = {ba.x, ba.y, ba.z, ba.w, bb.x, bb.y, bb.z, bb.w};
        short8 o;
#pragma unroll
        for (int j = 0; j < 8; ++j) {
            float t = bv[j] + dn * ((float)sv[j] + acc[j]);
            t = t > 0.f ? t : 0.f;
            o[j] = bf16_bits(t);
        }
        *(short8*)((short*)xb2 + (size_t)wid * 128 + c * 8) = o;
    }
}

// final scatter fused with output head: sigmoid(relu(h2) @ Wlin^T + blin)
__global__ __launch_bounds__(256) void k_scatter_out(
    const int* __restrict__ rowptr, const int2* __restrict__ meta,
    const float* __restrict__ deg, const _Float16* __restrict__ xlh,
    const float* __restrict__ bias, const float* __restrict__ wlin,
    const float* __restrict__ blin, float* __restrict__ out) {
    int wid = (blockIdx.x * blockDim.x + threadIdx.x) >> 6;
    int lane = threadIdx.x & 63;
    if (wid >= NN) return;
    int g = lane >> 4, c = lane & 15;
    float acc[8] = {0.f, 0.f, 0.f, 0.f, 0.f, 0.f, 0.f, 0.f};
    scatter_core(rowptr, meta, xlh, wid, g, c, acc);
    if (g == 0) {
        float dn = rsqrtf(deg[wid]);
        half8 sv = *(const half8*)(xlh + (size_t)wid * 128 + c * 8);
        const float4* bp = (const float4*)(bias + c * 8);
        float4 ba = bp[0], bb = bp[1];
        float bv[8] = {ba.x, ba.y, ba.z, ba.w, bb.x, bb.y, bb.z, bb.w};
        float p0 = 0.f, p1 = 0.f;
#pragma unroll
        for (int j = 0; j < 8; ++j) {
            float t = bv[j] + dn * ((float)sv[j] + acc[j]);
            t = t > 0.f ? t : 0.f;
            p0 += t * wlin[c * 8 + j];
            p1 += t * wlin[128 + c * 8 + j];
        }
#pragma unroll
        for (int off = 1; off < 16; off <<= 1) {
            p0 += __shfl_xor(p0, off, 64);
            p1 += __shfl_xor(p1, off, 64);
        }
        if (c == 0) {
            out[wid * 2 + 0] = 1.f / (1.f + __expf(-(p0 + blin[0])));
            out[wid * 2 + 1] = 1.f / (1.f + __expf(-(p1 + blin[1])));
        }
    }
}

// ---------------- host launcher ----------------

extern "C" void kernel_launch(void* const* d_in, const int* in_sizes, int n_in,
                              void* d_out, int out_size, void* d_ws, size_t ws_size,
                              hipStream_t stream) {
    const float* x = (const float*)d_in[0];
    const int* eidx_raw = (const int*)d_in[1];
    const float* W_p1 = (const float*)d_in[2];
    const float* b_p1 = (const float*)d_in[3];
    const float* W_p2 = (const float*)d_in[4];
    const float* b_p2 = (const float*)d_in[5];
    const float* W1 = (const float*)d_in[6];
    const float* b1 = (const float*)d_in[7];
    const float* W2 = (const float*)d_in[8];
    const float* b2 = (const float*)d_in[9];
    const float* W_lin = (const float*)d_in[10];
    const float* b_lin = (const float*)d_in[11];
    float* out = (float*)d_out;

    char* ws = (char*)d_ws;
    size_t off = 0;
    auto alloc = [&](size_t bytes) -> void* {
        off = (off + 255) & ~(size_t)255;
        void* p = ws + off;
        off += bytes;
        return p;
    };
    float* deg = (float*)alloc(NN * 4);
    int* rowptr = (int*)alloc((NN + 1) * 4);
    int* count = (int*)alloc((size_t)NN * CPAD * 4);  // line-padded histogram
    int* flag = (int*)alloc(4);
    int* bsums = (int*)alloc(128 * 4);
    int* rank = (int*)alloc((size_t)NE * 4);
    int2* meta = (int2*)alloc((size_t)NE * 8);
    __hip_bfloat16* xb = (__hip_bfloat16*)alloc((size_t)NN * 128 * 2);  // reused as xb2
    _Float16* xlh = (_Float16*)alloc((size_t)NN * 128 * 2);
    _Float16* uvh = (_Float16*)alloc((size_t)NN * 128 * 2);
    __hip_bfloat16* wcatb = (__hip_bfloat16*)alloc(128 * 128 * 2);
    __hip_bfloat16* w1b = (__hip_bfloat16*)alloc(128 * 128 * 2);
    __hip_bfloat16* w2b = (__hip_bfloat16*)alloc(128 * 128 * 2);

    const int TB = 256;
    int gN = (NN + TB - 1) / TB;        // 196
    int gS = (NN + 3) / 4;              // 12500

    // 1: weight cvt + count/bsums zero + layout flag
    k_init_cvt<<<gN, TB, 0, stream>>>(eidx_raw, count, flag, bsums, W_p1, W1, W2, wcatb, w1b, w2b);
    // 2: count+rank (prefix blocks, batched atomics) overlapped with uv GEMM
    k_uv_cnt<<<GCNT + GG, TB, 0, stream>>>(x, wcatb, b_p1, uvh, xb, eidx_raw, flag, count, rank);
    // 3: fused lookback scan -> rowptr
    k_scan_rowptr<<<98, 512, 0, stream>>>(count, bsums, rowptr);
    // 4: edge-ordered policy MLP + direct CSR fill
    k_pol_fill<<<GPOL, TB, 0, stream>>>(eidx_raw, flag, rank, rowptr, uvh, W_p2, b_p2, meta);
    // 5: layer-1 transform + deg (dinv folded into xlh)
    k_gemm<true><<<GG, TB, 0, stream>>>(xb, w1b, rowptr, meta, deg, xlh);
    // 6: layer-1 aggregate
    k_scatter_mid<<<gS, TB, 0, stream>>>(rowptr, meta, deg, xlh, b1, xb);
    // 7: layer-2 transform
    k_gemm<false><<<GG, TB, 0, stream>>>(xb, w2b, rowptr, meta, deg, xlh);
    // 8: layer-2 aggregate + output head
    k_scatter_out<<<gS, TB, 0, stream>>>(rowptr, meta, deg, xlh, b2, W_lin, b_lin, out);
}